// Round 7
// baseline (425.312 us; speedup 1.0000x reference)
//
#include <hip/hip_runtime.h>
#include <hip/hip_bf16.h>

// MoE SwiGLU MLP, sparse top-2 path.
// T=2048 tokens, D_MODEL=1024, D_FF=2048, E=8 experts, K=2.
// R8 349.0us (best): prep hidden under router (WgWu) + gu (Wd); gu 94us @
//     MfmaUtil 15.7% — barrier-drain latency-bound (2 barriers + vmcnt(0)
//     drain per 16 K-iters).
// R9 453us: direct-fp32 GEMM = L3 blowout. R10 379us: occupancy-3 thrashed L2
//     write-combining (WRITE 50->86MB); atomic combine +19us. Both reverted.
// R11: R8 base + 2-phase pipelined K-loops in both GEMMs (T3-minimum):
//     - A LDS tile dropped; A-frags read per-wave direct from global
//       (gu: xb gather, L2-hot; down: h_t already fragment-ordered, coalesced),
//       register-prefetched, issued BEFORE the glds16 batch (vmcnt ordering).
//     - B double-buffered glds16; ONE barrier per K-iter; stage issued before
//       MFMA so the drain lands after compute. gu LDS 64KB, down 32KB — both
//       2 blocks/CU.
//     Predict gu 94->55-70us, total 349 -> ~280-310us.

#define D_MODEL 1024
#define D_FF    2048
#define N_EXP   8
#define T_TOK   2048
#define MAXTILES 40   // sum_e ceil(cnt_e/128) <= 32+7 < 40

typedef __attribute__((ext_vector_type(8))) short bf16x8;
typedef __attribute__((ext_vector_type(8))) ushort u16x8;
typedef __attribute__((ext_vector_type(4))) float f32x4;

__device__ __forceinline__ ushort f2bf(float f) {
    union { float f; unsigned u; } c; c.f = f;
    unsigned u = c.u;
    return (ushort)((u + 0x7fffu + ((u >> 16) & 1u)) >> 16);  // RTNE
}

__device__ __forceinline__ void glds16(const void* g, void* l) {
    __builtin_amdgcn_global_load_lds(
        (const __attribute__((address_space(1))) unsigned int*)g,
        (__attribute__((address_space(3))) unsigned int*)l, 16, 0, 0);
}

// ---------------- prep helpers: fp32 -> bf16 tiled k-inner-8 (verified R6/R8) ----------------
__device__ __forceinline__ void prep_slab_gwu(
    int sp, int tid, const float* __restrict__ Wg, const float* __restrict__ Wu,
    ushort* __restrict__ Wgt, ushort* __restrict__ Wut, ushort* lds)
{
    int which = sp >> 10, s = sp & 1023;
    const float* src = which ? Wu : Wg;
    ushort* dst = which ? Wut : Wgt;
    int e = s >> 7, kt = (s >> 3) & 15, kb = s & 7;
    const float4* p = (const float4*)(src + (size_t)e * 1024 * 2048 + (size_t)(kt * 64 + kb * 8) * 2048);
#pragma unroll
    for (int i = 0; i < 16; i++) {
        float4 v = p[i * 256 + tid];
        ushort4 o;
        o.x = f2bf(v.x); o.y = f2bf(v.y); o.z = f2bf(v.z); o.w = f2bf(v.w);
        *(ushort4*)&lds[(i * 256 + tid) * 4] = o;
    }
    __syncthreads();
    u16x8 in[8];
#pragma unroll
    for (int ko = 0; ko < 8; ko++)
        in[ko] = *(const u16x8*)&lds[ko * 2048 + tid * 8];
    u16x8 out[8];
#pragma unroll
    for (int j = 0; j < 8; j++)
#pragma unroll
        for (int ko = 0; ko < 8; ko++)
            out[j][ko] = in[ko][j];
    __syncthreads();
    int swz = (tid & 7) << 4;
#pragma unroll
    for (int j = 0; j < 8; j++)
        *(u16x8*)((char*)lds + (((8 * tid + j) * 16) ^ swz)) = out[j];
    __syncthreads();
#pragma unroll
    for (int i = 0; i < 8; i++) {
        int c = i * 256 + tid;
        u16x8 v = *(const u16x8*)((char*)lds + ((c * 16) ^ (((c >> 3) & 7) << 4)));
        int R = c >> 7, q = c & 127;
        *(u16x8*)&dst[(size_t)(e * 256 + R * 16 + kt) * 8192 + kb * 1024 + q * 8] = v;
    }
}

__device__ __forceinline__ void prep_slab_wd(
    int s, int tid, const float* __restrict__ Wd, ushort* __restrict__ Wdt, ushort* lds)
{
    int e = s >> 7, kt = (s >> 2) & 31, kbp = s & 3;
    const float4* p = (const float4*)(Wd + (size_t)e * 2048 * 1024 + (size_t)(kt * 64 + kbp * 16) * 1024);
#pragma unroll
    for (int i = 0; i < 16; i++) {
        float4 v = p[i * 256 + tid];
        ushort4 o;
        o.x = f2bf(v.x); o.y = f2bf(v.y); o.z = f2bf(v.z); o.w = f2bf(v.w);
        *(ushort4*)&lds[(i * 256 + tid) * 4] = o;
    }
    __syncthreads();
    u16x8 in[8];
    int th = tid >> 7, tc = tid & 127;
#pragma unroll
    for (int ko = 0; ko < 8; ko++)
        in[ko] = *(const u16x8*)&lds[(th * 8 + ko) * 1024 + tc * 8];
    u16x8 out[8];
#pragma unroll
    for (int j = 0; j < 8; j++)
#pragma unroll
        for (int ko = 0; ko < 8; ko++)
            out[j][ko] = in[ko][j];
    __syncthreads();
    int swz = (tid & 7) << 4;
#pragma unroll
    for (int j = 0; j < 8; j++)
        *(u16x8*)((char*)lds + (((8 * tid + j) * 16) ^ swz)) = out[j];
    __syncthreads();
#pragma unroll
    for (int i = 0; i < 8; i++) {
        int c = i * 256 + tid;
        u16x8 v = *(const u16x8*)((char*)lds + ((c * 16) ^ (((c >> 3) & 7) << 4)));
        int R = c >> 7, q = c & 127;
        int kb2 = R >> 3, ntp = R & 7;
        *(u16x8*)&Wdt[(size_t)(e * 256 + ntp * 32 + kt) * 8192 + (kbp * 2 + kb2) * 1024 + q * 8] = v;
    }
}

// ---------------- launch 1: router (blocks 0..63) + Wg/Wu prep (64..2111) ----------------
union SM1 {
    float gws[N_EXP * D_MODEL];   // 32 KB router gate-weight cache
    ushort prep[16384];           // 32 KB prep scratch
};

__global__ __launch_bounds__(256) void k_router_prep(
    const float* __restrict__ x, const float* __restrict__ gw, const float* __restrict__ gb,
    int* cnt, float* probsum, int* tok, int* slotpk, float* wtok,
    ushort* __restrict__ xb,
    const float* __restrict__ Wg, const float* __restrict__ Wu,
    ushort* __restrict__ Wgt, ushort* __restrict__ Wut)
{
    __shared__ __align__(16) SM1 smem;
    __shared__ float ps_s[N_EXP];
    __shared__ int   bc_s[N_EXP];
    __shared__ int   gb_s[N_EXP];
    __shared__ int   a_e[64];
    __shared__ int   a_lp[64];

    int tid = threadIdx.x;
    int bid = blockIdx.x;

    if (bid >= 64) {                      // ---- prep role ----
        prep_slab_gwu(bid - 64, tid, Wg, Wu, Wgt, Wut, smem.prep);
        return;
    }

    // ---- router role ----
    float* gws = smem.gws;
    for (int i = tid; i < N_EXP * D_MODEL / 4; i += 256)
        ((float4*)gws)[i] = ((const float4*)gw)[i];
    if (tid < N_EXP) { ps_s[tid] = 0.f; bc_s[tid] = 0; }
    __syncthreads();

    int wave = tid >> 6, lane = tid & 63;

    for (int it = 0; it < 8; it++) {
        int tb = it * 4 + wave;                      // token-in-block
        int t = bid * 32 + tb;
        const float4* xr = (const float4*)(x + (size_t)t * D_MODEL);
        ushort* xbr = xb + (size_t)t * D_MODEL;

        float acc[N_EXP];
#pragma unroll
        for (int e = 0; e < N_EXP; e++) acc[e] = 0.f;
#pragma unroll
        for (int q = 0; q < 4; q++) {
            int idx = q * 64 + lane;
            float4 xv = xr[idx];
            ushort4 xc;
            xc.x = f2bf(xv.x); xc.y = f2bf(xv.y); xc.z = f2bf(xv.z); xc.w = f2bf(xv.w);
            *(ushort4*)&xbr[idx * 4] = xc;
#pragma unroll
            for (int e = 0; e < N_EXP; e++) {
                float4 gv = ((const float4*)(gws + e * D_MODEL))[idx];
                acc[e] += xv.x * gv.x + xv.y * gv.y + xv.z * gv.z + xv.w * gv.w;
            }
        }
#pragma unroll
        for (int off = 32; off > 0; off >>= 1) {
#pragma unroll
            for (int e = 0; e < N_EXP; e++) acc[e] += __shfl_xor(acc[e], off, 64);
        }
        if (lane == 0) {
            float l[N_EXP], m = -1e30f;
#pragma unroll
            for (int e = 0; e < N_EXP; e++) { l[e] = acc[e] + gb[e]; m = fmaxf(m, l[e]); }
            float p[N_EXP], s = 0.f;
#pragma unroll
            for (int e = 0; e < N_EXP; e++) { p[e] = expf(l[e] - m); s += p[e]; }
            float inv = 1.f / s;
#pragma unroll
            for (int e = 0; e < N_EXP; e++) { p[e] *= inv; atomicAdd(&ps_s[e], p[e]); }
            // top-2, lowest index wins ties (matches lax.top_k)
            int i0 = 0; float v0 = p[0];
#pragma unroll
            for (int e = 1; e < N_EXP; e++) if (p[e] > v0) { v0 = p[e]; i0 = e; }
            int i1 = -1; float v1 = -1.f;
#pragma unroll
            for (int e = 0; e < N_EXP; e++) if (e != i0 && p[e] > v1) { v1 = p[e]; i1 = e; }
            float winv = 1.f / (v0 + v1);
            int lp0 = atomicAdd(&bc_s[i0], 1);
            int lp1 = atomicAdd(&bc_s[i1], 1);
            a_e[tb * 2 + 0] = i0; a_lp[tb * 2 + 0] = lp0;
            a_e[tb * 2 + 1] = i1; a_lp[tb * 2 + 1] = lp1;
            wtok[t * 2 + 0] = v0 * winv;
            wtok[t * 2 + 1] = v1 * winv;
        }
    }
    __syncthreads();
    if (tid < N_EXP) {
        gb_s[tid] = atomicAdd(&cnt[tid], bc_s[tid]);
        atomicAdd(&probsum[tid], ps_s[tid]);
    }
    __syncthreads();
    if (tid < 64) {
        int tb = tid >> 1, k = tid & 1;
        int t = bid * 32 + tb;
        int e = a_e[tid];
        int slot = gb_s[e] + a_lp[tid];
        tok[e * T_TOK + slot] = t;
        slotpk[t * 2 + k] = (e << 16) | slot;
    }
}

// ---------------- 128-aligned expert bases + tile table + balance loss ----------------
__global__ void k_base_loss(const int* __restrict__ cnt, const float* __restrict__ probsum,
                            int* abase, int* tile, float* loss_out)
{
    if (threadIdx.x == 0 && blockIdx.x == 0) {
        int b = 0, nt = 0;
        float loss = 0.f;
        for (int e = 0; e < N_EXP; e++) {
            abase[e] = b;
            for (int m0 = 0; m0 < cnt[e]; m0 += 128)
                tile[nt++] = (e << 16) | m0;
            b += ((cnt[e] + 127) >> 7) * 128;           // capacity-aligned
            float mean = probsum[e] * (1.0f / T_TOK);
            loss += 0.125f * (logf(0.125f) - logf(mean + 1e-9f));
        }
        for (; nt < MAXTILES; nt++) tile[nt] = -1;
        *loss_out = loss;
    }
}

// ---------------- launch 3: pipelined gu-GEMM (0..639) + Wd prep (640..1663) ----------------
// 2-phase: B dbuf glds16 issued BEFORE MFMA, one barrier/iter; A-frags direct
// from xb (gather, L2-hot), ks0 prefetched one iter ahead, ks1 loaded early-in-iter
// BEFORE the glds16 batch so its vmcnt wait leaves the staging in flight.
struct SM_GU { ushort Bg[2][8192]; ushort Bu[2][8192]; };  // 64 KB
union SM3 {
    SM_GU g;
    ushort prep[16384]; // 32 KB prep scratch
};

__global__ __launch_bounds__(256, 2) void k_gu_prepwd(
    const ushort* __restrict__ Wgt, const ushort* __restrict__ Wut,
    const float* __restrict__ bg, const float* __restrict__ bu,
    const ushort* __restrict__ xb, const int* __restrict__ cnt,
    const int* __restrict__ abase, const int* __restrict__ tile,
    const int* __restrict__ tok, ushort* __restrict__ h_t,
    const float* __restrict__ Wd, ushort* __restrict__ Wdt)
{
    __shared__ __align__(16) SM3 smem;

    int bid = blockIdx.x;
    int tid = threadIdx.x;

    if (bid >= MAXTILES * 16) {           // ---- prep-Wd role ----
        prep_slab_wd(bid - MAXTILES * 16, tid, Wd, Wdt, smem.prep);
        return;
    }

    // ---- gu GEMM role ----
    int ti = tile[bid % MAXTILES];
    if (ti < 0) return;
    int e = ti >> 16, m0 = ti & 0xffff;
    int ne = cnt[e];
    int nt = bid / MAXTILES;                  // 0..15
    int n0 = nt * 128;
    int stile = (abase[e] >> 7) + (m0 >> 7);

    int lane = tid & 63, wave = tid >> 6;
    int wm = (wave & 1) * 64, wn = (wave >> 1) * 64;

    // A row pointers (token gather, clamped)
    const ushort* arowp[4];
#pragma unroll
    for (int s_ = 0; s_ < 4; s_++) {
        int pos = min(m0 + wm + (lane & 15) + s_ * 16, ne - 1);
        arowp[s_] = xb + (size_t)tok[e * T_TOK + pos] * D_MODEL;
    }
    int klo = (lane >> 4) * 8;                // ushort offset of this lane's k-octet

    const char* gbase = (const char*)(Wgt + (size_t)(e * 16 + nt) * 16 * 8192);
    const char* ubase = (const char*)(Wut + (size_t)(e * 16 + nt) * 16 * 8192);
    int goff = tid * 16;
    int loff = (tid >> 6) * 1024;

    ushort* Bg0 = smem.g.Bg[0]; ushort* Bg1 = smem.g.Bg[1];
    ushort* Bu0 = smem.g.Bu[0]; ushort* Bu1 = smem.g.Bu[1];

    f32x4 accg[4][4], accu[4][4];
#pragma unroll
    for (int i = 0; i < 4; i++)
#pragma unroll
        for (int j = 0; j < 4; j++) {
            accg[i][j] = (f32x4){0.f, 0.f, 0.f, 0.f};
            accu[i][j] = (f32x4){0.f, 0.f, 0.f, 0.f};
        }

    // prologue: stage kt=0 into buf0, prefetch A ks0 frags for kt=0
    bf16x8 afA[4], afB[4];
#pragma unroll
    for (int s_ = 0; s_ < 4; s_++)
        afA[s_] = *(const bf16x8*)(arowp[s_] + klo);
#pragma unroll
    for (int q = 0; q < 4; q++) {
        glds16(gbase + q * 4096 + goff, (char*)Bg0 + q * 4096 + loff);
        glds16(ubase + q * 4096 + goff, (char*)Bu0 + q * 4096 + loff);
    }
    __syncthreads();

    auto STEP = [&](int kt, bf16x8 (&afc)[4], bf16x8 (&afn)[4],
                    ushort* Bgc, ushort* Buc, ushort* Bgn, ushort* Bun) {
        // A ks1 frags for current kt (issued before glds16 -> waits leave staging in flight)
        bf16x8 af1[4];
#pragma unroll
        for (int s_ = 0; s_ < 4; s_++)
            af1[s_] = *(const bf16x8*)(arowp[s_] + kt * 64 + 32 + klo);
        if (kt < 15) {
            // A ks0 frags for next kt
#pragma unroll
            for (int s_ = 0; s_ < 4; s_++)
                afn[s_] = *(const bf16x8*)(arowp[s_] + (kt + 1) * 64 + klo);
            // B stage next kt into other buffer (flies during MFMA below)
            const char* gsrc = gbase + (kt + 1) * 16384;
            const char* usrc = ubase + (kt + 1) * 16384;
#pragma unroll
            for (int q = 0; q < 4; q++) {
                glds16(gsrc + q * 4096 + goff, (char*)Bgn + q * 4096 + loff);
                glds16(usrc + q * 4096 + goff, (char*)Bun + q * 4096 + loff);
            }
        }
        // ks = 0
#pragma unroll
        for (int sn = 0; sn < 4; sn++) {
            int ncol = wn + sn * 16 + (lane & 15);
            int bkb = lane >> 4;
            bf16x8 bgf = *(const bf16x8*)&Bgc[(bkb * 128 + ncol) * 8];
            bf16x8 buf_ = *(const bf16x8*)&Buc[(bkb * 128 + ncol) * 8];
#pragma unroll
            for (int s_ = 0; s_ < 4; s_++) {
                accg[s_][sn] = __builtin_amdgcn_mfma_f32_16x16x32_bf16(afc[s_], bgf, accg[s_][sn], 0, 0, 0);
                accu[s_][sn] = __builtin_amdgcn_mfma_f32_16x16x32_bf16(afc[s_], buf_, accu[s_][sn], 0, 0, 0);
            }
        }
        // ks = 1
#pragma unroll
        for (int sn = 0; sn < 4; sn++) {
            int ncol = wn + sn * 16 + (lane & 15);
            int bkb = 4 + (lane >> 4);
            bf16x8 bgf = *(const bf16x8*)&Bgc[(bkb * 128 + ncol) * 8];
            bf16x8 buf_ = *(const bf16x8*)&Buc[(bkb * 128 + ncol) * 8];
#pragma unroll
            for (int s_ = 0; s_ < 4; s_++) {
                accg[s_][sn] = __builtin_amdgcn_mfma_f32_16x16x32_bf16(af1[s_], bgf, accg[s_][sn], 0, 0, 0);
                accu[s_][sn] = __builtin_amdgcn_mfma_f32_16x16x32_bf16(af1[s_], buf_, accu[s_][sn], 0, 0, 0);
            }
        }
        __syncthreads();   // drains this iter's staging AFTER compute; guards dbuf reuse
    };

    for (int kt = 0; kt < 16; kt += 2) {
        STEP(kt,     afA, afB, Bg0, Bu0, Bg1, Bu1);
        STEP(kt + 1, afB, afA, Bg1, Bu1, Bg0, Bu0);
    }

    // epilogue: silu(g)*u -> h_t (bf16, tiled k-inner-8 for stage B's A-operand)
    int rbase = wm + ((lane >> 4) << 2);
    int cbase = wn + (lane & 15);
    size_t tbase = (size_t)stile * 32 * 8192;
#pragma unroll
    for (int sm_ = 0; sm_ < 4; sm_++) {
#pragma unroll
        for (int r = 0; r < 4; r++) {
            int pos = m0 + rbase + sm_ * 16 + r;
            if (pos < ne) {
                int row = pos & 127;
#pragma unroll
                for (int sn = 0; sn < 4; sn++) {
                    int col = n0 + cbase + sn * 16;
                    float g = accg[sm_][sn][r] + bg[e * D_FF + col];
                    float u = accu[sm_][sn][r] + bu[e * D_FF + col];
                    float hv = (g / (1.f + expf(-g))) * u;
                    int ktb = col >> 6, kb = (col >> 3) & 7, ko = col & 7;
                    h_t[tbase + (size_t)ktb * 8192 + (kb * 128 + row) * 8 + ko] = f2bf(hv);
                }
            }
        }
    }
}

// ---------------- stage B: outp = h @ Wd + bd (pipelined; A direct from h_t) ----------------
__global__ __launch_bounds__(256, 2) void k_expert_down(
    const ushort* __restrict__ Wdt, const float* __restrict__ bd,
    const ushort* __restrict__ h_t, const int* __restrict__ cnt,
    const int* __restrict__ abase, const int* __restrict__ tile,
    float* __restrict__ outp)
{
    int ti = tile[blockIdx.x];
    if (ti < 0) return;
    int e = ti >> 16, m0 = ti & 0xffff;
    int ne = cnt[e];
    int nt = blockIdx.y;                      // 0..7
    int n0 = nt * 128;
    int stile = (abase[e] >> 7) + (m0 >> 7);

    __shared__ __align__(16) ushort Bd_s[2][8192];    // 32 KB dbuf

    int tid = threadIdx.x;
    int lane = tid & 63, wave = tid >> 6;
    int wm = (wave & 1) * 64, wn = (wave >> 1) * 64;

    const char* hbase = (const char*)(h_t + (size_t)stile * 32 * 8192);
    const char* dbase = (const char*)(Wdt + (size_t)(e * 8 + nt) * 32 * 8192);
    int goff = tid * 16;
    int loff = (tid >> 6) * 1024;

    // A frag byte offsets inside a 16KB kt-tile (h_t is fragment-ordered: coalesced)
    int arow_f = wm + (lane & 15);
    int a0off[4], a1off[4];
#pragma unroll
    for (int s_ = 0; s_ < 4; s_++) {
        a0off[s_] = ((lane >> 4) * 128 + arow_f + s_ * 16) * 16;
        a1off[s_] = ((4 + (lane >> 4)) * 128 + arow_f + s_ * 16) * 16;
    }

    ushort* Bd0 = Bd_s[0]; ushort* Bd1 = Bd_s[1];

    f32x4 acc[4][4];
#pragma unroll
    for (int i = 0; i < 4; i++)
#pragma unroll
        for (int j = 0; j < 4; j++) acc[i][j] = (f32x4){0.f, 0.f, 0.f, 0.f};

    // prologue
    bf16x8 afA[4], afB[4];
#pragma unroll
    for (int s_ = 0; s_ < 4; s_++)
        afA[s_] = *(const bf16x8*)(hbase + a0off[s_]);
#pragma unroll
    for (int q = 0; q < 4; q++)
        glds16(dbase + q * 4096 + goff, (char*)Bd0 + q * 4096 + loff);
    __syncthreads();

    auto STEP = [&](int kt, bf16x8 (&afc)[4], bf16x8 (&afn)[4],
                    ushort* Bdc, ushort* Bdn) {
        bf16x8 af1[4];
#pragma unroll
        for (int s_ = 0; s_ < 4; s_++)
            af1[s_] = *(const bf16x8*)(hbase + kt * 16384 + a1off[s_]);
        if (kt < 31) {
#pragma unroll
            for (int s_ = 0; s_ < 4; s_++)
                afn[s_] = *(const bf16x8*)(hbase + (kt + 1) * 16384 + a0off[s_]);
            const char* bsrc = dbase + (kt + 1) * 16384;
#pragma unroll
            for (int q = 0; q < 4; q++)
                glds16(bsrc + q * 4096 + goff, (char*)Bdn + q * 4096 + loff);
        }
        // ks = 0
#pragma unroll
        for (int sn = 0; sn < 4; sn++) {
            int ncol = wn + sn * 16 + (lane & 15);
            int bkb = lane >> 4;
            bf16x8 bdf = *(const bf16x8*)&Bdc[(bkb * 128 + ncol) * 8];
#pragma unroll
            for (int s_ = 0; s_ < 4; s_++)
                acc[s_][sn] = __builtin_amdgcn_mfma_f32_16x16x32_bf16(afc[s_], bdf, acc[s_][sn], 0, 0, 0);
        }
        // ks = 1
#pragma unroll
        for (int sn = 0; sn < 4; sn++) {
            int ncol = wn + sn * 16 + (lane & 15);
            int bkb = 4 + (lane >> 4);
            bf16x8 bdf = *(const bf16x8*)&Bdc[(bkb * 128 + ncol) * 8];
#pragma unroll
            for (int s_ = 0; s_ < 4; s_++)
                acc[s_][sn] = __builtin_amdgcn_mfma_f32_16x16x32_bf16(af1[s_], bdf, acc[s_][sn], 0, 0, 0);
        }
        __syncthreads();
    };

    for (int kt = 0; kt < 32; kt += 2) {
        STEP(kt,     afA, afB, Bd0, Bd1);
        STEP(kt + 1, afB, afA, Bd1, Bd0);
    }

    int rbase = wm + ((lane >> 4) << 2);
    int cbase = wn + (lane & 15);
#pragma unroll
    for (int sm_ = 0; sm_ < 4; sm_++) {
#pragma unroll
        for (int r = 0; r < 4; r++) {
            int pos = m0 + rbase + sm_ * 16 + r;
            if (pos < ne) {
                size_t ob = (size_t)(abase[e] + pos) * D_MODEL;
#pragma unroll
                for (int sn = 0; sn < 4; sn++) {
                    int col = n0 + cbase + sn * 16;
                    outp[ob + col] = acc[sm_][sn][r] + bd[e * D_MODEL + col];
                }
            }
        }
    }
}

// ---------------- combine: y[t] = w0*outp[slot0] + w1*outp[slot1] ----------------
__global__ void k_combine(const float* __restrict__ outp, const int* __restrict__ slotpk,
                          const float* __restrict__ wtok, const int* __restrict__ abase,
                          float* __restrict__ y)
{
    int idx = blockIdx.x * 256 + threadIdx.x;   // 524288 float4s
    int t = idx >> 8, j = idx & 255;
    int sp0 = slotpk[t * 2 + 0], sp1 = slotpk[t * 2 + 1];
    float w0 = wtok[t * 2 + 0], w1 = wtok[t * 2 + 1];
    size_t s0 = (size_t)abase[sp0 >> 16] + (sp0 & 0xffff);
    size_t s1 = (size_t)abase[sp1 >> 16] + (sp1 & 0xffff);
    float4 a = ((const float4*)outp)[s0 * (D_MODEL / 4) + j];
    float4 b = ((const float4*)outp)[s1 * (D_MODEL / 4) + j];
    float4 o;
    o.x = w0 * a.x + w1 * b.x;
    o.y = w0 * a.y + w1 * b.y;
    o.z = w0 * a.z + w1 * b.z;
    o.w = w0 * a.w + w1 * b.w;
    ((float4*)y)[idx] = o;
}

extern "C" void kernel_launch(void* const* d_in, const int* in_sizes, int n_in,
                              void* d_out, int out_size, void* d_ws, size_t ws_size,
                              hipStream_t stream)
{
    const float* x  = (const float*)d_in[0];
    const float* gw = (const float*)d_in[1];
    const float* gb = (const float*)d_in[2];
    const float* Wg = (const float*)d_in[3];
    const float* bg = (const float*)d_in[4];
    const float* Wu = (const float*)d_in[5];
    const float* bu = (const float*)d_in[6];
    const float* Wd = (const float*)d_in[7];
    const float* bd = (const float*)d_in[8];
    float* y = (float*)d_out;
    float* loss_out = y + (size_t)T_TOK * D_MODEL;

    char* ws = (char*)d_ws;
    int*    cnt     = (int*)(ws + 0);             // 8 ints   [zeroed]
    float*  probsum = (float*)(ws + 128);         // 8 floats [zeroed]
    int*    abase   = (int*)(ws + 256);           // 8 ints
    int*    tiletab = (int*)(ws + 320);           // MAXTILES ints
    int*    slotpk  = (int*)(ws + 512);           // 4096 ints
    float*  wtok    = (float*)(ws + 16896);       // 4096 floats
    int*    tok     = (int*)(ws + 33280);         // 8*2048 ints
    ushort* xb      = (ushort*)(ws + 131072);     // 2M bf16 = 4 MB
    ushort* Wgt     = (ushort*)(ws + 4325376);    // 33.55 MB tiled bf16
    ushort* Wut     = (ushort*)(ws + 37879808);   // 33.55 MB
    ushort* Wdt     = (ushort*)(ws + 71434240);   // 33.55 MB
    ushort* h_t     = (ushort*)(ws + 104988672);  // 20.97 MB
    float*  outp    = (float*)(ws + 125960192);   // 20.97 MB
    // total ws use: ~147 MB

    (void)hipMemsetAsync(d_ws, 0, 256, stream);
    // launch 1: router (64 blocks) overlapped with Wg/Wu prep (2048 blocks)
    k_router_prep<<<dim3(64 + 2048), dim3(256), 0, stream>>>(
        x, gw, gb, cnt, probsum, tok, slotpk, wtok, xb, Wg, Wu, Wgt, Wut);
    k_base_loss<<<dim3(1), dim3(64), 0, stream>>>(cnt, probsum, abase, tiletab, loss_out);
    // launch 3: pipelined gu GEMM (640) overlapped with Wd prep (1024)
    k_gu_prepwd<<<dim3(MAXTILES * 16 + 1024), dim3(256), 0, stream>>>(
        Wgt, Wut, bg, bu, xb, cnt, abase, tiletab, tok, h_t, Wd, Wdt);
    // launch 4: pipelined down GEMM
    k_expert_down<<<dim3(MAXTILES, 8), dim3(256), 0, stream>>>(
        Wdt, bd, h_t, cnt, abase, tiletab, outp);
    k_combine<<<dim3(2048), dim3(256), 0, stream>>>(outp, slotpk, wtok, abase, y);
}

// Round 8
// 401.103 us; speedup vs baseline: 1.0604x; 1.0604x over previous
//
#include <hip/hip_runtime.h>
#include <hip/hip_bf16.h>

// MoE SwiGLU MLP, sparse top-2 path.
// T=2048 tokens, D_MODEL=1024, D_FF=2048, E=8 experts, K=2.
// R8 349.0us (best): prep hidden under router (WgWu) + gu (Wd).
// R9 453us: all-fp32-direct GEMMs -> L3 blowout (201MB fp32 working set).
// R10 379us: occupancy-3 + atomic combine, both regressed. R11 425us: barrier
//     still drains vmcnt(0) -> "pipelined" 2-phase was an illusion; scattered
//     A-gather added latency. All reverted.
// R12: R8 design minus the Wd prep. gu launch runs PURE (640 blocks, R8 inner
//     loop). down consumes fp32 Wd directly with R9's reg-staged cvt kernel:
//     down's working set (Wd 67MB fp32 + h_t 21MB) fits L3, so the ~4x panel
//     re-reads are L3-served (R9's failure was the COMBINED 201MB set).
//     Removes prep_slab_wd + 1024 blocks + ~150MB traffic from gu launch.
//     Predict gu 94->55-70us, down 40-55us, total 349 -> ~310-325us.

#define D_MODEL 1024
#define D_FF    2048
#define N_EXP   8
#define T_TOK   2048
#define MAXTILES 40   // sum_e ceil(cnt_e/128) <= 32+7 < 40

typedef __attribute__((ext_vector_type(8))) short bf16x8;
typedef __attribute__((ext_vector_type(8))) ushort u16x8;
typedef __attribute__((ext_vector_type(4))) float f32x4;

__device__ __forceinline__ ushort f2bf(float f) {
    union { float f; unsigned u; } c; c.f = f;
    unsigned u = c.u;
    return (ushort)((u + 0x7fffu + ((u >> 16) & 1u)) >> 16);  // RTNE
}

__device__ __forceinline__ void glds16(const void* g, void* l) {
    __builtin_amdgcn_global_load_lds(
        (const __attribute__((address_space(1))) unsigned int*)g,
        (__attribute__((address_space(3))) unsigned int*)l, 16, 0, 0);
}

// ---------------- prep helper: Wg/Wu fp32 -> bf16 tiled k-inner-8 (verified R6/R8) ----------------
// Output layout: tile t*8192 ushorts; within tile [(kb*128+ncol)*8+ko],
// k = kt*64 + kb*8 + ko. Wg/Wu: t = e*256 + nt*16 + kt.
__device__ __forceinline__ void prep_slab_gwu(
    int sp, int tid, const float* __restrict__ Wg, const float* __restrict__ Wu,
    ushort* __restrict__ Wgt, ushort* __restrict__ Wut, ushort* lds)
{
    int which = sp >> 10, s = sp & 1023;
    const float* src = which ? Wu : Wg;
    ushort* dst = which ? Wut : Wgt;
    int e = s >> 7, kt = (s >> 3) & 15, kb = s & 7;
    const float4* p = (const float4*)(src + (size_t)e * 1024 * 2048 + (size_t)(kt * 64 + kb * 8) * 2048);
#pragma unroll
    for (int i = 0; i < 16; i++) {
        float4 v = p[i * 256 + tid];
        ushort4 o;
        o.x = f2bf(v.x); o.y = f2bf(v.y); o.z = f2bf(v.z); o.w = f2bf(v.w);
        *(ushort4*)&lds[(i * 256 + tid) * 4] = o;
    }
    __syncthreads();
    u16x8 in[8];
#pragma unroll
    for (int ko = 0; ko < 8; ko++)
        in[ko] = *(const u16x8*)&lds[ko * 2048 + tid * 8];
    u16x8 out[8];
#pragma unroll
    for (int j = 0; j < 8; j++)
#pragma unroll
        for (int ko = 0; ko < 8; ko++)
            out[j][ko] = in[ko][j];
    __syncthreads();
    int swz = (tid & 7) << 4;
#pragma unroll
    for (int j = 0; j < 8; j++)
        *(u16x8*)((char*)lds + (((8 * tid + j) * 16) ^ swz)) = out[j];
    __syncthreads();
#pragma unroll
    for (int i = 0; i < 8; i++) {
        int c = i * 256 + tid;
        u16x8 v = *(const u16x8*)((char*)lds + ((c * 16) ^ (((c >> 3) & 7) << 4)));
        int R = c >> 7, q = c & 127;
        *(u16x8*)&dst[(size_t)(e * 256 + R * 16 + kt) * 8192 + kb * 1024 + q * 8] = v;
    }
}

// ---------------- launch 1: router (blocks 0..63) + Wg/Wu prep (64..2111) ----------------
union SM1 {
    float gws[N_EXP * D_MODEL];   // 32 KB router gate-weight cache
    ushort prep[16384];           // 32 KB prep scratch
};

__global__ __launch_bounds__(256) void k_router_prep(
    const float* __restrict__ x, const float* __restrict__ gw, const float* __restrict__ gb,
    int* cnt, float* probsum, int* tok, int* slotpk, float* wtok,
    ushort* __restrict__ xb,
    const float* __restrict__ Wg, const float* __restrict__ Wu,
    ushort* __restrict__ Wgt, ushort* __restrict__ Wut)
{
    __shared__ __align__(16) SM1 smem;
    __shared__ float ps_s[N_EXP];
    __shared__ int   bc_s[N_EXP];
    __shared__ int   gb_s[N_EXP];
    __shared__ int   a_e[64];
    __shared__ int   a_lp[64];

    int tid = threadIdx.x;
    int bid = blockIdx.x;

    if (bid >= 64) {                      // ---- prep role ----
        prep_slab_gwu(bid - 64, tid, Wg, Wu, Wgt, Wut, smem.prep);
        return;
    }

    // ---- router role ----
    float* gws = smem.gws;
    for (int i = tid; i < N_EXP * D_MODEL / 4; i += 256)
        ((float4*)gws)[i] = ((const float4*)gw)[i];
    if (tid < N_EXP) { ps_s[tid] = 0.f; bc_s[tid] = 0; }
    __syncthreads();

    int wave = tid >> 6, lane = tid & 63;

    for (int it = 0; it < 8; it++) {
        int tb = it * 4 + wave;                      // token-in-block
        int t = bid * 32 + tb;
        const float4* xr = (const float4*)(x + (size_t)t * D_MODEL);
        ushort* xbr = xb + (size_t)t * D_MODEL;

        float acc[N_EXP];
#pragma unroll
        for (int e = 0; e < N_EXP; e++) acc[e] = 0.f;
#pragma unroll
        for (int q = 0; q < 4; q++) {
            int idx = q * 64 + lane;
            float4 xv = xr[idx];
            ushort4 xc;
            xc.x = f2bf(xv.x); xc.y = f2bf(xv.y); xc.z = f2bf(xv.z); xc.w = f2bf(xv.w);
            *(ushort4*)&xbr[idx * 4] = xc;
#pragma unroll
            for (int e = 0; e < N_EXP; e++) {
                float4 gv = ((const float4*)(gws + e * D_MODEL))[idx];
                acc[e] += xv.x * gv.x + xv.y * gv.y + xv.z * gv.z + xv.w * gv.w;
            }
        }
#pragma unroll
        for (int off = 32; off > 0; off >>= 1) {
#pragma unroll
            for (int e = 0; e < N_EXP; e++) acc[e] += __shfl_xor(acc[e], off, 64);
        }
        if (lane == 0) {
            float l[N_EXP], m = -1e30f;
#pragma unroll
            for (int e = 0; e < N_EXP; e++) { l[e] = acc[e] + gb[e]; m = fmaxf(m, l[e]); }
            float p[N_EXP], s = 0.f;
#pragma unroll
            for (int e = 0; e < N_EXP; e++) { p[e] = expf(l[e] - m); s += p[e]; }
            float inv = 1.f / s;
#pragma unroll
            for (int e = 0; e < N_EXP; e++) { p[e] *= inv; atomicAdd(&ps_s[e], p[e]); }
            // top-2, lowest index wins ties (matches lax.top_k)
            int i0 = 0; float v0 = p[0];
#pragma unroll
            for (int e = 1; e < N_EXP; e++) if (p[e] > v0) { v0 = p[e]; i0 = e; }
            int i1 = -1; float v1 = -1.f;
#pragma unroll
            for (int e = 0; e < N_EXP; e++) if (e != i0 && p[e] > v1) { v1 = p[e]; i1 = e; }
            float winv = 1.f / (v0 + v1);
            int lp0 = atomicAdd(&bc_s[i0], 1);
            int lp1 = atomicAdd(&bc_s[i1], 1);
            a_e[tb * 2 + 0] = i0; a_lp[tb * 2 + 0] = lp0;
            a_e[tb * 2 + 1] = i1; a_lp[tb * 2 + 1] = lp1;
            wtok[t * 2 + 0] = v0 * winv;
            wtok[t * 2 + 1] = v1 * winv;
        }
    }
    __syncthreads();
    if (tid < N_EXP) {
        gb_s[tid] = atomicAdd(&cnt[tid], bc_s[tid]);
        atomicAdd(&probsum[tid], ps_s[tid]);
    }
    __syncthreads();
    if (tid < 64) {
        int tb = tid >> 1, k = tid & 1;
        int t = bid * 32 + tb;
        int e = a_e[tid];
        int slot = gb_s[e] + a_lp[tid];
        tok[e * T_TOK + slot] = t;
        slotpk[t * 2 + k] = (e << 16) | slot;
    }
}

// ---------------- 128-aligned expert bases + tile table + balance loss ----------------
__global__ void k_base_loss(const int* __restrict__ cnt, const float* __restrict__ probsum,
                            int* abase, int* tile, float* loss_out)
{
    if (threadIdx.x == 0 && blockIdx.x == 0) {
        int b = 0, nt = 0;
        float loss = 0.f;
        for (int e = 0; e < N_EXP; e++) {
            abase[e] = b;
            for (int m0 = 0; m0 < cnt[e]; m0 += 128)
                tile[nt++] = (e << 16) | m0;
            b += ((cnt[e] + 127) >> 7) * 128;           // capacity-aligned
            float mean = probsum[e] * (1.0f / T_TOK);
            loss += 0.125f * (logf(0.125f) - logf(mean + 1e-9f));
        }
        for (; nt < MAXTILES; nt++) tile[nt] = -1;
        *loss_out = loss;
    }
}

// ---------------- stage A: h = silu(x@Wg + bg) * (x@Wu + bu) ----------------
// R8's proven 128x128 tile, BK=64, 4 waves, dual accumulators, As stride 88.
// B via glds16 from pre-tiled bf16 weights; A gathered (tok) with uint4 copies.
__global__ __launch_bounds__(256, 2) void k_expert_gu(
    const ushort* __restrict__ Wgt, const ushort* __restrict__ Wut,
    const float* __restrict__ bg, const float* __restrict__ bu,
    const ushort* __restrict__ xb, const int* __restrict__ cnt,
    const int* __restrict__ abase, const int* __restrict__ tile,
    const int* __restrict__ tok, ushort* __restrict__ h_t)
{
    int ti = tile[blockIdx.x];
    if (ti < 0) return;                       // contiguous tail only
    int e = ti >> 16, m0 = ti & 0xffff;
    int ne = cnt[e];
    int nt = blockIdx.y;                      // 0..15
    int n0 = nt * 128;
    int stile = (abase[e] >> 7) + (m0 >> 7);  // global aligned slot-tile

    __shared__ __align__(16) ushort As[128 * 88];     // stride 88: 16B aligned, 2-way banks
    __shared__ __align__(16) ushort Bg_s[8192];       // k-inner-8 image (16KB)
    __shared__ __align__(16) ushort Bu_s[8192];

    int tid = threadIdx.x;
    int lane = tid & 63, wave = tid >> 6;
    int wm = (wave & 1) * 64, wn = (wave >> 1) * 64;

    // A staging: thread -> (row, k-half)
    int arow = tid >> 1;
    int akh = (tid & 1) * 32;
    int atok = tok[e * T_TOK + min(m0 + arow, ne - 1)];
    const ushort* xrow = xb + (size_t)atok * D_MODEL;

    // B tile bases (16KB per kt)
    const char* gbase = (const char*)(Wgt + (size_t)(e * 16 + nt) * 16 * 8192);
    const char* ubase = (const char*)(Wut + (size_t)(e * 16 + nt) * 16 * 8192);
    int goff = tid * 16;                      // per-lane global byte offset in tile
    int loff = (tid >> 6) * 1024;             // wave-uniform LDS byte offset

    f32x4 accg[4][4], accu[4][4];
#pragma unroll
    for (int i = 0; i < 4; i++)
#pragma unroll
        for (int j = 0; j < 4; j++) {
            accg[i][j] = (f32x4){0.f, 0.f, 0.f, 0.f};
            accu[i][j] = (f32x4){0.f, 0.f, 0.f, 0.f};
        }

    for (int kt = 0; kt < D_MODEL / 64; kt++) {
        __syncthreads();
        // A tile: bf16 gather copy, 16B chunks
#pragma unroll
        for (int q = 0; q < 4; q++)
            *(uint4*)&As[arow * 88 + akh + q * 8] = *(const uint4*)&xrow[kt * 64 + akh + q * 8];
        // B tiles: direct-to-LDS block copy (16KB each)
        const char* gsrc = gbase + kt * 16384;
        const char* usrc = ubase + kt * 16384;
#pragma unroll
        for (int q = 0; q < 4; q++) {
            glds16(gsrc + q * 4096 + goff, (char*)Bg_s + q * 4096 + loff);
            glds16(usrc + q * 4096 + goff, (char*)Bu_s + q * 4096 + loff);
        }
        __syncthreads();
        // compute
#pragma unroll
        for (int ks = 0; ks < 2; ks++) {
            bf16x8 af[4];
            int arow_f = wm + (lane & 15);
            int akb = ks * 32 + (lane >> 4) * 8;
#pragma unroll
            for (int sm_ = 0; sm_ < 4; sm_++)
                af[sm_] = *(const bf16x8*)&As[(arow_f + sm_ * 16) * 88 + akb];
            int bkb = ks * 4 + (lane >> 4);
#pragma unroll
            for (int sn = 0; sn < 4; sn++) {
                int ncol = wn + sn * 16 + (lane & 15);
                bf16x8 bgf = *(const bf16x8*)&Bg_s[(bkb * 128 + ncol) * 8];
                bf16x8 buf = *(const bf16x8*)&Bu_s[(bkb * 128 + ncol) * 8];
#pragma unroll
                for (int sm_ = 0; sm_ < 4; sm_++) {
                    accg[sm_][sn] = __builtin_amdgcn_mfma_f32_16x16x32_bf16(af[sm_], bgf, accg[sm_][sn], 0, 0, 0);
                    accu[sm_][sn] = __builtin_amdgcn_mfma_f32_16x16x32_bf16(af[sm_], buf, accu[sm_][sn], 0, 0, 0);
                }
            }
        }
    }
    // epilogue: silu(g)*u -> h_t (bf16, tiled k-inner-8 for stage B's A-operand)
    int rbase = wm + ((lane >> 4) << 2);
    int cbase = wn + (lane & 15);
    size_t tbase = (size_t)stile * 32 * 8192;
#pragma unroll
    for (int sm_ = 0; sm_ < 4; sm_++) {
#pragma unroll
        for (int r = 0; r < 4; r++) {
            int pos = m0 + rbase + sm_ * 16 + r;
            if (pos < ne) {
                int row = pos & 127;
#pragma unroll
                for (int sn = 0; sn < 4; sn++) {
                    int col = n0 + cbase + sn * 16;
                    float g = accg[sm_][sn][r] + bg[e * D_FF + col];
                    float u = accu[sm_][sn][r] + bu[e * D_FF + col];
                    float hv = (g / (1.f + expf(-g))) * u;
                    int ktb = col >> 6, kb = (col >> 3) & 7, ko = col & 7;
                    h_t[tbase + (size_t)ktb * 8192 + (kb * 128 + row) * 8 + ko] = f2bf(hv);
                }
            }
        }
    }
}

// ---------------- stage B: outp = h @ Wd + bd (A reg-copied, B fp32-cvt staged; R9-verified) ----------------
// Wd fp32 (67MB) + h_t (21MB) fit L3 -> panel re-reads are L3-served.
// Reg prefetch crosses barriers legitimately (data held in VGPRs, no glds16).
__global__ __launch_bounds__(256, 2) void k_expert_down(
    const float* __restrict__ Wd, const float* __restrict__ bd,
    const ushort* __restrict__ h_t, const int* __restrict__ cnt,
    const int* __restrict__ abase, const int* __restrict__ tile,
    float* __restrict__ outp)
{
    int ti = tile[blockIdx.x];
    if (ti < 0) return;
    int e = ti >> 16, m0 = ti & 0xffff;
    int ne = cnt[e];
    int nt = blockIdx.y;                      // 0..7
    int n0 = nt * 128;
    int stile = (abase[e] >> 7) + (m0 >> 7);

    __shared__ __align__(16) ushort As8[8192];        // k-inner-8 image (16KB)
    __shared__ __align__(16) ushort Bd_s[8192];

    int tid = threadIdx.x;
    int lane = tid & 63, wave = tid >> 6;
    int wm = (wave & 1) * 64, wn = (wave >> 1) * 64;

    const uint4* hbase = (const uint4*)(h_t + (size_t)stile * 32 * 8192);  // 1024 uint4 per kt

    int skb = tid >> 5, sc4 = (tid & 31) * 4;
    const float* dp = Wd + (size_t)e * D_FF * D_MODEL + (size_t)(skb * 8) * D_MODEL + n0 + sc4;
    ushort* dds = Bd_s + (skb * 128 + sc4) * 8;

    f32x4 acc[4][4];
#pragma unroll
    for (int i = 0; i < 4; i++)
#pragma unroll
        for (int j = 0; j < 4; j++) acc[i][j] = (f32x4){0.f, 0.f, 0.f, 0.f};

    // preload kt=0
    uint4 va[4];
    float4 vd[8];
#pragma unroll
    for (int q = 0; q < 4; q++) va[q] = hbase[q * 256 + tid];
#pragma unroll
    for (int j = 0; j < 8; j++) vd[j] = *(const float4*)(dp + (size_t)j * D_MODEL);

    for (int kt = 0; kt < D_FF / 64; kt++) {
        __syncthreads();
        // A: linear 16KB copy from held regs
#pragma unroll
        for (int q = 0; q < 4; q++) ((uint4*)As8)[q * 256 + tid] = va[q];
        // B: cvt held regs -> k-inner-8 bf16
        u16x8 d0, d1, d2, d3;
#pragma unroll
        for (int j = 0; j < 8; j++) {
            d0[j] = f2bf(vd[j].x); d1[j] = f2bf(vd[j].y); d2[j] = f2bf(vd[j].z); d3[j] = f2bf(vd[j].w);
        }
        *(u16x8*)(dds + 0)  = d0; *(u16x8*)(dds + 8)  = d1;
        *(u16x8*)(dds + 16) = d2; *(u16x8*)(dds + 24) = d3;
        // prefetch next kt (flies during MFMA; lives in regs across the barrier)
        if (kt < D_FF / 64 - 1) {
            const uint4* hn = hbase + (kt + 1) * 1024;
            const float* dn = dp + (size_t)(kt + 1) * 64 * D_MODEL;
#pragma unroll
            for (int q = 0; q < 4; q++) va[q] = hn[q * 256 + tid];
#pragma unroll
            for (int j = 0; j < 8; j++) vd[j] = *(const float4*)(dn + (size_t)j * D_MODEL);
        }
        __syncthreads();
#pragma unroll
        for (int ks = 0; ks < 2; ks++) {
            bf16x8 af[4];
            int kb = ks * 4 + (lane >> 4);
            int arow_f = wm + (lane & 15);
#pragma unroll
            for (int sm_ = 0; sm_ < 4; sm_++)
                af[sm_] = *(const bf16x8*)&As8[(kb * 128 + arow_f + sm_ * 16) * 8];
#pragma unroll
            for (int sn = 0; sn < 4; sn++) {
                int ncol = wn + sn * 16 + (lane & 15);
                bf16x8 bdf = *(const bf16x8*)&Bd_s[(kb * 128 + ncol) * 8];
#pragma unroll
                for (int sm_ = 0; sm_ < 4; sm_++)
                    acc[sm_][sn] = __builtin_amdgcn_mfma_f32_16x16x32_bf16(af[sm_], bdf, acc[sm_][sn], 0, 0, 0);
            }
        }
    }
    int rbase = wm + ((lane >> 4) << 2);
    int cbase = wn + (lane & 15);
#pragma unroll
    for (int sm_ = 0; sm_ < 4; sm_++) {
#pragma unroll
        for (int r = 0; r < 4; r++) {
            int pos = m0 + rbase + sm_ * 16 + r;
            if (pos < ne) {
                size_t ob = (size_t)(abase[e] + pos) * D_MODEL;
#pragma unroll
                for (int sn = 0; sn < 4; sn++) {
                    int col = n0 + cbase + sn * 16;
                    outp[ob + col] = acc[sm_][sn][r] + bd[e * D_MODEL + col];
                }
            }
        }
    }
}

// ---------------- combine: y[t] = w0*outp[slot0] + w1*outp[slot1] ----------------
__global__ void k_combine(const float* __restrict__ outp, const int* __restrict__ slotpk,
                          const float* __restrict__ wtok, const int* __restrict__ abase,
                          float* __restrict__ y)
{
    int idx = blockIdx.x * 256 + threadIdx.x;   // 524288 float4s
    int t = idx >> 8, j = idx & 255;
    int sp0 = slotpk[t * 2 + 0], sp1 = slotpk[t * 2 + 1];
    float w0 = wtok[t * 2 + 0], w1 = wtok[t * 2 + 1];
    size_t s0 = (size_t)abase[sp0 >> 16] + (sp0 & 0xffff);
    size_t s1 = (size_t)abase[sp1 >> 16] + (sp1 & 0xffff);
    float4 a = ((const float4*)outp)[s0 * (D_MODEL / 4) + j];
    float4 b = ((const float4*)outp)[s1 * (D_MODEL / 4) + j];
    float4 o;
    o.x = w0 * a.x + w1 * b.x;
    o.y = w0 * a.y + w1 * b.y;
    o.z = w0 * a.z + w1 * b.z;
    o.w = w0 * a.w + w1 * b.w;
    ((float4*)y)[idx] = o;
}

extern "C" void kernel_launch(void* const* d_in, const int* in_sizes, int n_in,
                              void* d_out, int out_size, void* d_ws, size_t ws_size,
                              hipStream_t stream)
{
    const float* x  = (const float*)d_in[0];
    const float* gw = (const float*)d_in[1];
    const float* gb = (const float*)d_in[2];
    const float* Wg = (const float*)d_in[3];
    const float* bg = (const float*)d_in[4];
    const float* Wu = (const float*)d_in[5];
    const float* bu = (const float*)d_in[6];
    const float* Wd = (const float*)d_in[7];
    const float* bd = (const float*)d_in[8];
    float* y = (float*)d_out;
    float* loss_out = y + (size_t)T_TOK * D_MODEL;

    char* ws = (char*)d_ws;
    int*    cnt     = (int*)(ws + 0);             // 8 ints   [zeroed]
    float*  probsum = (float*)(ws + 128);         // 8 floats [zeroed]
    int*    abase   = (int*)(ws + 256);           // 8 ints
    int*    tiletab = (int*)(ws + 320);           // MAXTILES ints
    int*    slotpk  = (int*)(ws + 512);           // 4096 ints
    float*  wtok    = (float*)(ws + 16896);       // 4096 floats
    int*    tok     = (int*)(ws + 33280);         // 8*2048 ints
    ushort* xb      = (ushort*)(ws + 131072);     // 2M bf16 = 4 MB
    ushort* Wgt     = (ushort*)(ws + 4325376);    // 33.55 MB tiled bf16
    ushort* Wut     = (ushort*)(ws + 37879808);   // 33.55 MB
    ushort* h_t     = (ushort*)(ws + 71434240);   // 20.97 MB
    float*  outp    = (float*)(ws + 92405760);    // 20.97 MB
    // total ws use: ~113 MB

    (void)hipMemsetAsync(d_ws, 0, 256, stream);
    // launch 1: router (64 blocks) overlapped with Wg/Wu prep (2048 blocks)
    k_router_prep<<<dim3(64 + 2048), dim3(256), 0, stream>>>(
        x, gw, gb, cnt, probsum, tok, slotpk, wtok, xb, Wg, Wu, Wgt, Wut);
    k_base_loss<<<dim3(1), dim3(64), 0, stream>>>(cnt, probsum, abase, tiletab, loss_out);
    // launch 3: pure gu GEMM (R8 inner loop)
    k_expert_gu<<<dim3(MAXTILES, 16), dim3(256), 0, stream>>>(
        Wgt, Wut, bg, bu, xb, cnt, abase, tiletab, tok, h_t);
    // launch 4: down GEMM, fp32 Wd direct (L3-resident working set)
    k_expert_down<<<dim3(MAXTILES, 8), dim3(256), 0, stream>>>(
        Wd, bd, h_t, cnt, abase, tiletab, outp);
    k_combine<<<dim3(2048), dim3(256), 0, stream>>>(outp, slotpk, wtok, abase, y);
}

// Round 9
// 350.925 us; speedup vs baseline: 1.2120x; 1.1430x over previous
//
#include <hip/hip_runtime.h>
#include <hip/hip_bf16.h>

// MoE SwiGLU MLP, sparse top-2 path.
// T=2048 tokens, D_MODEL=1024, D_FF=2048, E=8 experts, K=2.
// R8 349.0us (best): prep hidden under router (WgWu) + gu (Wd); both GEMMs on
//     prepped bf16 tiles. R9/R12: fp32-direct weights fail (HBM re-reads; L3
//     doesn't hold fp32 working sets) — permanently ruled out. R10: occ-3 +
//     atomic combine regressed. R11: __syncthreads always drains vmcnt ->
//     source-level pipelining is an illusion.
// R12 counters exposed down: Occupancy 8.4%, MfmaUtil 6% @ 320 blocks —
//     parallelism-starved (1.25 blocks/CU), 32 serial barrier-pairs/block.
// R13: R8 restored EXACTLY + down retiled M128->M64: grid (80,8)=640 blocks
//     (2.5/CU), per-block MFMA 4096->2048, barrier chain halved. A-stage 8KB/kt
//     (row-half via m0&64 -> +1024B per kb block), B-stage unchanged. LDS 24KB.
//     Wdt re-read 8x instead of 4x — bf16 L3-served (proven regime).
//     Predict down ->65-80us, total 349 -> ~305-320us.

#define D_MODEL 1024
#define D_FF    2048
#define N_EXP   8
#define T_TOK   2048
#define MAXTILES 40   // 128-row tiles: sum_e ceil(cnt_e/128) <= 32+7 < 40
#define MAXT64   80   // 64-row tiles:  sum_e ceil(cnt_e/64)  <= 64+8 < 80

typedef __attribute__((ext_vector_type(8))) short bf16x8;
typedef __attribute__((ext_vector_type(8))) ushort u16x8;
typedef __attribute__((ext_vector_type(4))) float f32x4;

__device__ __forceinline__ ushort f2bf(float f) {
    union { float f; unsigned u; } c; c.f = f;
    unsigned u = c.u;
    return (ushort)((u + 0x7fffu + ((u >> 16) & 1u)) >> 16);  // RTNE
}

__device__ __forceinline__ void glds16(const void* g, void* l) {
    __builtin_amdgcn_global_load_lds(
        (const __attribute__((address_space(1))) unsigned int*)g,
        (__attribute__((address_space(3))) unsigned int*)l, 16, 0, 0);
}

// ---------------- prep helpers: fp32 -> bf16, tiled k-inner-8 (verified R6/R8) ----------------
// Output layout: tile t*8192 ushorts; within tile [(kb*128+ncol)*8+ko],
// k = kt*64 + kb*8 + ko. Wg/Wu: t = e*256 + nt*16 + kt. Wd: t = e*256 + nt*32 + kt.
__device__ __forceinline__ void prep_slab_gwu(
    int sp, int tid, const float* __restrict__ Wg, const float* __restrict__ Wu,
    ushort* __restrict__ Wgt, ushort* __restrict__ Wut, ushort* lds)
{
    int which = sp >> 10, s = sp & 1023;
    const float* src = which ? Wu : Wg;
    ushort* dst = which ? Wut : Wgt;
    int e = s >> 7, kt = (s >> 3) & 15, kb = s & 7;
    const float4* p = (const float4*)(src + (size_t)e * 1024 * 2048 + (size_t)(kt * 64 + kb * 8) * 2048);
#pragma unroll
    for (int i = 0; i < 16; i++) {
        float4 v = p[i * 256 + tid];
        ushort4 o;
        o.x = f2bf(v.x); o.y = f2bf(v.y); o.z = f2bf(v.z); o.w = f2bf(v.w);
        *(ushort4*)&lds[(i * 256 + tid) * 4] = o;
    }
    __syncthreads();
    u16x8 in[8];
#pragma unroll
    for (int ko = 0; ko < 8; ko++)
        in[ko] = *(const u16x8*)&lds[ko * 2048 + tid * 8];
    u16x8 out[8];
#pragma unroll
    for (int j = 0; j < 8; j++)
#pragma unroll
        for (int ko = 0; ko < 8; ko++)
            out[j][ko] = in[ko][j];
    __syncthreads();
    int swz = (tid & 7) << 4;
#pragma unroll
    for (int j = 0; j < 8; j++)
        *(u16x8*)((char*)lds + (((8 * tid + j) * 16) ^ swz)) = out[j];
    __syncthreads();
#pragma unroll
    for (int i = 0; i < 8; i++) {
        int c = i * 256 + tid;
        u16x8 v = *(const u16x8*)((char*)lds + ((c * 16) ^ (((c >> 3) & 7) << 4)));
        int R = c >> 7, q = c & 127;
        *(u16x8*)&dst[(size_t)(e * 256 + R * 16 + kt) * 8192 + kb * 1024 + q * 8] = v;
    }
}

__device__ __forceinline__ void prep_slab_wd(
    int s, int tid, const float* __restrict__ Wd, ushort* __restrict__ Wdt, ushort* lds)
{
    int e = s >> 7, kt = (s >> 2) & 31, kbp = s & 3;
    const float4* p = (const float4*)(Wd + (size_t)e * 2048 * 1024 + (size_t)(kt * 64 + kbp * 16) * 1024);
#pragma unroll
    for (int i = 0; i < 16; i++) {
        float4 v = p[i * 256 + tid];
        ushort4 o;
        o.x = f2bf(v.x); o.y = f2bf(v.y); o.z = f2bf(v.z); o.w = f2bf(v.w);
        *(ushort4*)&lds[(i * 256 + tid) * 4] = o;
    }
    __syncthreads();
    u16x8 in[8];
    int th = tid >> 7, tc = tid & 127;
#pragma unroll
    for (int ko = 0; ko < 8; ko++)
        in[ko] = *(const u16x8*)&lds[(th * 8 + ko) * 1024 + tc * 8];
    u16x8 out[8];
#pragma unroll
    for (int j = 0; j < 8; j++)
#pragma unroll
        for (int ko = 0; ko < 8; ko++)
            out[j][ko] = in[ko][j];
    __syncthreads();
    int swz = (tid & 7) << 4;
#pragma unroll
    for (int j = 0; j < 8; j++)
        *(u16x8*)((char*)lds + (((8 * tid + j) * 16) ^ swz)) = out[j];
    __syncthreads();
#pragma unroll
    for (int i = 0; i < 8; i++) {
        int c = i * 256 + tid;
        u16x8 v = *(const u16x8*)((char*)lds + ((c * 16) ^ (((c >> 3) & 7) << 4)));
        int R = c >> 7, q = c & 127;
        int kb2 = R >> 3, ntp = R & 7;
        *(u16x8*)&Wdt[(size_t)(e * 256 + ntp * 32 + kt) * 8192 + (kbp * 2 + kb2) * 1024 + q * 8] = v;
    }
}

// ---------------- launch 1: router (blocks 0..63) + Wg/Wu prep (64..2111) ----------------
union SM1 {
    float gws[N_EXP * D_MODEL];   // 32 KB router gate-weight cache
    ushort prep[16384];           // 32 KB prep scratch
};

__global__ __launch_bounds__(256) void k_router_prep(
    const float* __restrict__ x, const float* __restrict__ gw, const float* __restrict__ gb,
    int* cnt, float* probsum, int* tok, int* slotpk, float* wtok,
    ushort* __restrict__ xb,
    const float* __restrict__ Wg, const float* __restrict__ Wu,
    ushort* __restrict__ Wgt, ushort* __restrict__ Wut)
{
    __shared__ __align__(16) SM1 smem;
    __shared__ float ps_s[N_EXP];
    __shared__ int   bc_s[N_EXP];
    __shared__ int   gb_s[N_EXP];
    __shared__ int   a_e[64];
    __shared__ int   a_lp[64];

    int tid = threadIdx.x;
    int bid = blockIdx.x;

    if (bid >= 64) {                      // ---- prep role ----
        prep_slab_gwu(bid - 64, tid, Wg, Wu, Wgt, Wut, smem.prep);
        return;
    }

    // ---- router role ----
    float* gws = smem.gws;
    for (int i = tid; i < N_EXP * D_MODEL / 4; i += 256)
        ((float4*)gws)[i] = ((const float4*)gw)[i];
    if (tid < N_EXP) { ps_s[tid] = 0.f; bc_s[tid] = 0; }
    __syncthreads();

    int wave = tid >> 6, lane = tid & 63;

    for (int it = 0; it < 8; it++) {
        int tb = it * 4 + wave;                      // token-in-block
        int t = bid * 32 + tb;
        const float4* xr = (const float4*)(x + (size_t)t * D_MODEL);
        ushort* xbr = xb + (size_t)t * D_MODEL;

        float acc[N_EXP];
#pragma unroll
        for (int e = 0; e < N_EXP; e++) acc[e] = 0.f;
#pragma unroll
        for (int q = 0; q < 4; q++) {
            int idx = q * 64 + lane;
            float4 xv = xr[idx];
            ushort4 xc;
            xc.x = f2bf(xv.x); xc.y = f2bf(xv.y); xc.z = f2bf(xv.z); xc.w = f2bf(xv.w);
            *(ushort4*)&xbr[idx * 4] = xc;
#pragma unroll
            for (int e = 0; e < N_EXP; e++) {
                float4 gv = ((const float4*)(gws + e * D_MODEL))[idx];
                acc[e] += xv.x * gv.x + xv.y * gv.y + xv.z * gv.z + xv.w * gv.w;
            }
        }
#pragma unroll
        for (int off = 32; off > 0; off >>= 1) {
#pragma unroll
            for (int e = 0; e < N_EXP; e++) acc[e] += __shfl_xor(acc[e], off, 64);
        }
        if (lane == 0) {
            float l[N_EXP], m = -1e30f;
#pragma unroll
            for (int e = 0; e < N_EXP; e++) { l[e] = acc[e] + gb[e]; m = fmaxf(m, l[e]); }
            float p[N_EXP], s = 0.f;
#pragma unroll
            for (int e = 0; e < N_EXP; e++) { p[e] = expf(l[e] - m); s += p[e]; }
            float inv = 1.f / s;
#pragma unroll
            for (int e = 0; e < N_EXP; e++) { p[e] *= inv; atomicAdd(&ps_s[e], p[e]); }
            // top-2, lowest index wins ties (matches lax.top_k)
            int i0 = 0; float v0 = p[0];
#pragma unroll
            for (int e = 1; e < N_EXP; e++) if (p[e] > v0) { v0 = p[e]; i0 = e; }
            int i1 = -1; float v1 = -1.f;
#pragma unroll
            for (int e = 0; e < N_EXP; e++) if (e != i0 && p[e] > v1) { v1 = p[e]; i1 = e; }
            float winv = 1.f / (v0 + v1);
            int lp0 = atomicAdd(&bc_s[i0], 1);
            int lp1 = atomicAdd(&bc_s[i1], 1);
            a_e[tb * 2 + 0] = i0; a_lp[tb * 2 + 0] = lp0;
            a_e[tb * 2 + 1] = i1; a_lp[tb * 2 + 1] = lp1;
            wtok[t * 2 + 0] = v0 * winv;
            wtok[t * 2 + 1] = v1 * winv;
        }
    }
    __syncthreads();
    if (tid < N_EXP) {
        gb_s[tid] = atomicAdd(&cnt[tid], bc_s[tid]);
        atomicAdd(&probsum[tid], ps_s[tid]);
    }
    __syncthreads();
    if (tid < 64) {
        int tb = tid >> 1, k = tid & 1;
        int t = bid * 32 + tb;
        int e = a_e[tid];
        int slot = gb_s[e] + a_lp[tid];
        tok[e * T_TOK + slot] = t;
        slotpk[t * 2 + k] = (e << 16) | slot;
    }
}

// ---------------- 128-aligned expert bases + tile tables + balance loss ----------------
__global__ void k_base_loss(const int* __restrict__ cnt, const float* __restrict__ probsum,
                            int* abase, int* tile, int* tile64, float* loss_out)
{
    if (threadIdx.x == 0 && blockIdx.x == 0) {
        int b = 0, nt = 0, n64 = 0;
        float loss = 0.f;
        for (int e = 0; e < N_EXP; e++) {
            abase[e] = b;
            for (int m0 = 0; m0 < cnt[e]; m0 += 128)
                tile[nt++] = (e << 16) | m0;
            for (int m0 = 0; m0 < cnt[e]; m0 += 64)
                tile64[n64++] = (e << 16) | m0;
            b += ((cnt[e] + 127) >> 7) * 128;           // capacity-aligned
            float mean = probsum[e] * (1.0f / T_TOK);
            loss += 0.125f * (logf(0.125f) - logf(mean + 1e-9f));
        }
        for (; nt < MAXTILES; nt++) tile[nt] = -1;
        for (; n64 < MAXT64; n64++) tile64[n64] = -1;
        *loss_out = loss;
    }
}

// ---------------- launch 3: stage A gu-GEMM (0..639) + Wd prep (640..1663) ----------------
// R8's proven structure: 128x128 tile, BK=64, 4 waves, dual acc, As stride 88.
struct SM_GU { ushort As[128 * 88]; ushort Bg[8192]; ushort Bu[8192]; };
union SM3 {
    SM_GU g;            // 54.5 KB gemm
    ushort prep[16384]; // 32 KB prep scratch
};

__global__ __launch_bounds__(256, 2) void k_gu_prepwd(
    const ushort* __restrict__ Wgt, const ushort* __restrict__ Wut,
    const float* __restrict__ bg, const float* __restrict__ bu,
    const ushort* __restrict__ xb, const int* __restrict__ cnt,
    const int* __restrict__ abase, const int* __restrict__ tile,
    const int* __restrict__ tok, ushort* __restrict__ h_t,
    const float* __restrict__ Wd, ushort* __restrict__ Wdt)
{
    __shared__ __align__(16) SM3 smem;

    int bid = blockIdx.x;
    int tid = threadIdx.x;

    if (bid >= MAXTILES * 16) {           // ---- prep-Wd role ----
        prep_slab_wd(bid - MAXTILES * 16, tid, Wd, Wdt, smem.prep);
        return;
    }

    // ---- gu GEMM role (R8-verbatim) ----
    int ti = tile[bid % MAXTILES];
    if (ti < 0) return;
    int e = ti >> 16, m0 = ti & 0xffff;
    int ne = cnt[e];
    int nt = bid / MAXTILES;                  // 0..15
    int n0 = nt * 128;
    int stile = (abase[e] >> 7) + (m0 >> 7);

    ushort* As = smem.g.As;
    ushort* Bg_s = smem.g.Bg;
    ushort* Bu_s = smem.g.Bu;

    int lane = tid & 63, wave = tid >> 6;
    int wm = (wave & 1) * 64, wn = (wave >> 1) * 64;

    int arow = tid >> 1;
    int akh = (tid & 1) * 32;
    int atok = tok[e * T_TOK + min(m0 + arow, ne - 1)];
    const ushort* xrow = xb + (size_t)atok * D_MODEL;

    const char* gbase = (const char*)(Wgt + (size_t)(e * 16 + nt) * 16 * 8192);
    const char* ubase = (const char*)(Wut + (size_t)(e * 16 + nt) * 16 * 8192);
    int goff = tid * 16;
    int loff = (tid >> 6) * 1024;

    f32x4 accg[4][4], accu[4][4];
#pragma unroll
    for (int i = 0; i < 4; i++)
#pragma unroll
        for (int j = 0; j < 4; j++) {
            accg[i][j] = (f32x4){0.f, 0.f, 0.f, 0.f};
            accu[i][j] = (f32x4){0.f, 0.f, 0.f, 0.f};
        }

    for (int kt = 0; kt < D_MODEL / 64; kt++) {
        __syncthreads();
#pragma unroll
        for (int q = 0; q < 4; q++)
            *(uint4*)&As[arow * 88 + akh + q * 8] = *(const uint4*)&xrow[kt * 64 + akh + q * 8];
        const char* gsrc = gbase + kt * 16384;
        const char* usrc = ubase + kt * 16384;
#pragma unroll
        for (int q = 0; q < 4; q++) {
            glds16(gsrc + q * 4096 + goff, (char*)Bg_s + q * 4096 + loff);
            glds16(usrc + q * 4096 + goff, (char*)Bu_s + q * 4096 + loff);
        }
        __syncthreads();
#pragma unroll
        for (int ks = 0; ks < 2; ks++) {
            bf16x8 af[4];
            int arow_f = wm + (lane & 15);
            int akb = ks * 32 + (lane >> 4) * 8;
#pragma unroll
            for (int sm_ = 0; sm_ < 4; sm_++)
                af[sm_] = *(const bf16x8*)&As[(arow_f + sm_ * 16) * 88 + akb];
            int bkb = ks * 4 + (lane >> 4);
#pragma unroll
            for (int sn = 0; sn < 4; sn++) {
                int ncol = wn + sn * 16 + (lane & 15);
                bf16x8 bgf = *(const bf16x8*)&Bg_s[(bkb * 128 + ncol) * 8];
                bf16x8 buf = *(const bf16x8*)&Bu_s[(bkb * 128 + ncol) * 8];
#pragma unroll
                for (int sm_ = 0; sm_ < 4; sm_++) {
                    accg[sm_][sn] = __builtin_amdgcn_mfma_f32_16x16x32_bf16(af[sm_], bgf, accg[sm_][sn], 0, 0, 0);
                    accu[sm_][sn] = __builtin_amdgcn_mfma_f32_16x16x32_bf16(af[sm_], buf, accu[sm_][sn], 0, 0, 0);
                }
            }
        }
    }
    // epilogue: silu(g)*u -> h_t (bf16, tiled k-inner-8 for stage B's A-operand)
    int rbase = wm + ((lane >> 4) << 2);
    int cbase = wn + (lane & 15);
    size_t tbase = (size_t)stile * 32 * 8192;
#pragma unroll
    for (int sm_ = 0; sm_ < 4; sm_++) {
#pragma unroll
        for (int r = 0; r < 4; r++) {
            int pos = m0 + rbase + sm_ * 16 + r;
            if (pos < ne) {
                int row = pos & 127;
#pragma unroll
                for (int sn = 0; sn < 4; sn++) {
                    int col = n0 + cbase + sn * 16;
                    float g = accg[sm_][sn][r] + bg[e * D_FF + col];
                    float u = accu[sm_][sn][r] + bu[e * D_FF + col];
                    float hv = (g / (1.f + expf(-g))) * u;
                    int ktb = col >> 6, kb = (col >> 3) & 7, ko = col & 7;
                    h_t[tbase + (size_t)ktb * 8192 + (kb * 128 + row) * 8 + ko] = f2bf(hv);
                }
            }
        }
    }
}

// ---------------- stage B: outp = h @ Wd + bd — 64x128 tiles, 640 blocks ----------------
// 4 waves: wm in {0,32}, wn in {0,64}; acc[2][4]. A-stage 8KB/kt (2 glds16),
// row-half of the 128-slot h_t tile selected by (m0 & 64) -> +1024B per kb block.
__global__ __launch_bounds__(256, 2) void k_expert_down(
    const ushort* __restrict__ Wdt, const float* __restrict__ bd,
    const ushort* __restrict__ h_t, const int* __restrict__ cnt,
    const int* __restrict__ abase, const int* __restrict__ tile64,
    float* __restrict__ outp)
{
    int ti = tile64[blockIdx.x];
    if (ti < 0) return;
    int e = ti >> 16, m0 = ti & 0xffff;       // m0 multiple of 64
    int ne = cnt[e];
    int nt = blockIdx.y;                      // 0..7
    int n0 = nt * 128;
    int stile = (abase[e] >> 7) + (m0 >> 7);
    int hoff = (m0 & 64) ? 1024 : 0;          // byte offset of row-half in each kb block

    __shared__ __align__(16) ushort As8[4096];        // [kb 0..7][row 0..63][ko 0..7] (8KB)
    __shared__ __align__(16) ushort Bd_s[8192];       // k-inner-8 image (16KB)

    int tid = threadIdx.x;
    int lane = tid & 63, wave = tid >> 6;
    int wm = (wave & 1) * 32, wn = (wave >> 1) * 64;

    const char* hbase = (const char*)(h_t + (size_t)stile * 32 * 8192);
    const char* dbase = (const char*)(Wdt + (size_t)(e * 8 + nt) * 32 * 8192);
    int goff = tid * 16;
    int loff = (tid >> 6) * 1024;

    f32x4 acc[2][4];
#pragma unroll
    for (int i = 0; i < 2; i++)
#pragma unroll
        for (int j = 0; j < 4; j++) acc[i][j] = (f32x4){0.f, 0.f, 0.f, 0.f};

    for (int kt = 0; kt < D_FF / 64; kt++) {
        __syncthreads();
        // A: 8KB (64 rows x 64 k), 2 chunks/thread; chunk c -> kb = c>>6, row = c&63
#pragma unroll
        for (int q = 0; q < 2; q++) {
            int c = q * 256 + tid;
            int kb = c >> 6;
            glds16(hbase + kt * 16384 + kb * 2048 + hoff + (c & 63) * 16,
                   (char*)As8 + q * 4096 + loff);
        }
        // B: 16KB
        const char* bsrc = dbase + kt * 16384;
#pragma unroll
        for (int q = 0; q < 4; q++)
            glds16(bsrc + q * 4096 + goff, (char*)Bd_s + q * 4096 + loff);
        __syncthreads();
#pragma unroll
        for (int ks = 0; ks < 2; ks++) {
            int kb = ks * 4 + (lane >> 4);
            int arow_l = wm + (lane & 15);
            bf16x8 af[2];
#pragma unroll
            for (int sm_ = 0; sm_ < 2; sm_++)
                af[sm_] = *(const bf16x8*)&As8[(kb * 64 + arow_l + sm_ * 16) * 8];
#pragma unroll
            for (int sn = 0; sn < 4; sn++) {
                int ncol = wn + sn * 16 + (lane & 15);
                bf16x8 bdf = *(const bf16x8*)&Bd_s[(kb * 128 + ncol) * 8];
#pragma unroll
                for (int sm_ = 0; sm_ < 2; sm_++)
                    acc[sm_][sn] = __builtin_amdgcn_mfma_f32_16x16x32_bf16(af[sm_], bdf, acc[sm_][sn], 0, 0, 0);
            }
        }
    }
    int rbase = wm + ((lane >> 4) << 2);
    int cbase = wn + (lane & 15);
#pragma unroll
    for (int sm_ = 0; sm_ < 2; sm_++) {
#pragma unroll
        for (int r = 0; r < 4; r++) {
            int pos = m0 + rbase + sm_ * 16 + r;
            if (pos < ne) {
                size_t ob = (size_t)(abase[e] + pos) * D_MODEL;
#pragma unroll
                for (int sn = 0; sn < 4; sn++) {
                    int col = n0 + cbase + sn * 16;
                    outp[ob + col] = acc[sm_][sn][r] + bd[e * D_MODEL + col];
                }
            }
        }
    }
}

// ---------------- combine: y[t] = w0*outp[slot0] + w1*outp[slot1] ----------------
__global__ void k_combine(const float* __restrict__ outp, const int* __restrict__ slotpk,
                          const float* __restrict__ wtok, const int* __restrict__ abase,
                          float* __restrict__ y)
{
    int idx = blockIdx.x * 256 + threadIdx.x;   // 524288 float4s
    int t = idx >> 8, j = idx & 255;
    int sp0 = slotpk[t * 2 + 0], sp1 = slotpk[t * 2 + 1];
    float w0 = wtok[t * 2 + 0], w1 = wtok[t * 2 + 1];
    size_t s0 = (size_t)abase[sp0 >> 16] + (sp0 & 0xffff);
    size_t s1 = (size_t)abase[sp1 >> 16] + (sp1 & 0xffff);
    float4 a = ((const float4*)outp)[s0 * (D_MODEL / 4) + j];
    float4 b = ((const float4*)outp)[s1 * (D_MODEL / 4) + j];
    float4 o;
    o.x = w0 * a.x + w1 * b.x;
    o.y = w0 * a.y + w1 * b.y;
    o.z = w0 * a.z + w1 * b.z;
    o.w = w0 * a.w + w1 * b.w;
    ((float4*)y)[idx] = o;
}

extern "C" void kernel_launch(void* const* d_in, const int* in_sizes, int n_in,
                              void* d_out, int out_size, void* d_ws, size_t ws_size,
                              hipStream_t stream)
{
    const float* x  = (const float*)d_in[0];
    const float* gw = (const float*)d_in[1];
    const float* gb = (const float*)d_in[2];
    const float* Wg = (const float*)d_in[3];
    const float* bg = (const float*)d_in[4];
    const float* Wu = (const float*)d_in[5];
    const float* bu = (const float*)d_in[6];
    const float* Wd = (const float*)d_in[7];
    const float* bd = (const float*)d_in[8];
    float* y = (float*)d_out;
    float* loss_out = y + (size_t)T_TOK * D_MODEL;

    char* ws = (char*)d_ws;
    int*    cnt     = (int*)(ws + 0);             // 8 ints   [zeroed]
    float*  probsum = (float*)(ws + 128);         // 8 floats [zeroed]
    int*    abase   = (int*)(ws + 256);           // 8 ints
    int*    tiletab = (int*)(ws + 320);           // MAXTILES ints (ends 480)
    int*    slotpk  = (int*)(ws + 512);           // 4096 ints
    float*  wtok    = (float*)(ws + 16896);       // 4096 floats
    int*    tok     = (int*)(ws + 33280);         // 8*2048 ints (ends 98816)
    int*    tile64  = (int*)(ws + 98816);         // MAXT64 ints (ends 99136)
    ushort* xb      = (ushort*)(ws + 131072);     // 2M bf16 = 4 MB
    ushort* Wgt     = (ushort*)(ws + 4325376);    // 33.55 MB tiled bf16
    ushort* Wut     = (ushort*)(ws + 37879808);   // 33.55 MB
    ushort* Wdt     = (ushort*)(ws + 71434240);   // 33.55 MB
    ushort* h_t     = (ushort*)(ws + 104988672);  // 20.97 MB
    float*  outp    = (float*)(ws + 125960192);   // 20.97 MB
    // total ws use: ~147 MB

    (void)hipMemsetAsync(d_ws, 0, 256, stream);
    // launch 1: router (64 blocks) overlapped with Wg/Wu prep (2048 blocks)
    k_router_prep<<<dim3(64 + 2048), dim3(256), 0, stream>>>(
        x, gw, gb, cnt, probsum, tok, slotpk, wtok, xb, Wg, Wu, Wgt, Wut);
    k_base_loss<<<dim3(1), dim3(64), 0, stream>>>(cnt, probsum, abase, tiletab, tile64, loss_out);
    // launch 3: gu GEMM (640 blocks) overlapped with Wd prep (1024 blocks)
    k_gu_prepwd<<<dim3(MAXTILES * 16 + 1024), dim3(256), 0, stream>>>(
        Wgt, Wut, bg, bu, xb, cnt, abase, tiletab, tok, h_t, Wd, Wdt);
    // launch 4: down GEMM, 64-row tiles (640 blocks)
    k_expert_down<<<dim3(MAXT64, 8), dim3(256), 0, stream>>>(
        Wdt, bd, h_t, cnt, abase, tile64, outp);
    k_combine<<<dim3(2048), dim3(256), 0, stream>>>(outp, slotpk, wtok, abase, y);
}